// Round 5
// baseline (223.095 us; speedup 1.0000x reference)
//
#include <hip/hip_runtime.h>

constexpr int kB = 32;      // batch
constexpr int kA = 8400;    // anchors total (80*80 + 40*40 + 20*20)
constexpr int kG = 60;      // max GTs
constexpr int kC = 80;      // classes
constexpr int kK = 10;      // top-k
constexpr int kNBx = (kA + 255)/256;    // 33 blocks per batch (loss)
constexpr int kNB = kNBx * kB;          // 1056 loss blocks
constexpr int kNDx = (kA + 127)/128;    // 66 decode blocks per batch (2 thr/anchor)

// ---- HW-native fast math ----
__device__ __forceinline__ float fexp(float x){ return __expf(x); }
__device__ __forceinline__ float flog(float x){ return __logf(x); }
__device__ __forceinline__ float frcp(float x){ return __builtin_amdgcn_rcpf(x); }
__device__ __forceinline__ float frsq(float x){ return __builtin_amdgcn_rsqf(x); }
__device__ __forceinline__ float fsqrt(float x){ return __builtin_amdgcn_sqrtf(x); }
__device__ __forceinline__ float fdiv(float a, float b){ return a * __builtin_amdgcn_rcpf(b); }
__device__ __forceinline__ float sigm(float x){ return frcp(1.0f + fexp(-x)); }
__device__ __forceinline__ float bce(float x, float t){
  return fmaxf(x, 0.0f) - x*t + flog(1.0f + fexp(-fabsf(x)));
}

// monotone float -> u32 (total order)
__device__ __forceinline__ unsigned ordbits(float v){
  unsigned u = __float_as_uint(v);
  return (u & 0x80000000u) ? ~u : (u | 0x80000000u);
}
__device__ __forceinline__ float unpackf(unsigned k){
  return __uint_as_float((k & 0x80000000u) ? (k & 0x7fffffffu) : ~k);
}

struct AInfo { int x, y; float st; };
__device__ __forceinline__ AInfo ainfo(int a){
  AInfo r;
  if (a < 6400)      { r.x = a % 80;           r.y = a / 80;           r.st = 8.0f;  }
  else if (a < 8000) { int l = a-6400; r.x = l % 40; r.y = l / 40;     r.st = 16.0f; }
  else               { int l = a-8000; r.x = l % 20; r.y = l / 20;     r.st = 32.0f; }
  return r;
}

__device__ __forceinline__ float featv(const float* __restrict__ f8,
                                       const float* __restrict__ f16,
                                       const float* __restrict__ f32x,
                                       int b, int ch, int a){
  if (a < 6400) return f8 [(b*85 + ch)*6400 + a];
  if (a < 8000) return f16[(b*85 + ch)*1600 + (a - 6400)];
  return             f32x[(b*85 + ch)*400  + (a - 8000)];
}

__device__ __forceinline__ float pair_iou(float4 g, float4 p){
  float tlx = fmaxf(g.x - g.z*0.5f, p.x - p.z*0.5f);
  float tly = fmaxf(g.y - g.w*0.5f, p.y - p.w*0.5f);
  float brx = fminf(g.x + g.z*0.5f, p.x + p.z*0.5f);
  float bry = fminf(g.y + g.w*0.5f, p.y + p.w*0.5f);
  float inter = (tlx < brx && tly < bry) ? (brx-tlx)*(bry-tly) : 0.0f;
  return fdiv(inter, g.z*g.w + p.z*p.w - inter + 1e-16f);
}

// cost given precomputed iou and obj sigmoid — shared by k_assign / k_loss
__device__ __forceinline__ float cost_core(float iou, float cl, float obs, float b0sum,
                                           int a, float4 gt, int fg_a){
  AInfo ai = ainfo(a);
  float cx = ((float)ai.x + 0.5f)*ai.st;
  float cy = ((float)ai.y + 0.5f)*ai.st;
  bool in_box = (cx > gt.x - 0.5f*gt.z) && (cx < gt.x + 0.5f*gt.z)
             && (cy > gt.y - 0.5f*gt.w) && (cy < gt.y + 0.5f*gt.w);
  bool in_ctr = (cx > gt.x - 2.5f*ai.st) && (cx < gt.x + 2.5f*ai.st)
             && (cy > gt.y - 2.5f*ai.st) && (cy < gt.y + 2.5f*ai.st);
  float p = fsqrt(sigm(cl) * obs);
  p = fminf(fmaxf(p, 1e-7f), 1.0f - 1e-7f);
  float diff = -flog(p) + flog(1.0f - p);      // bce1 - bce0 at class cls
  float c = b0sum + diff;
  c += 3.0f * (-flog(iou + 1e-8f));
  c += (in_box && in_ctr) ? 0.0f : 100000.0f;
  c += fg_a ? 0.0f : 1000000000.0f;
  return c;
}

__device__ __forceinline__ unsigned long long wave_max64(unsigned long long v){
  #pragma unroll
  for (int off = 32; off; off >>= 1){
    unsigned long long o = __shfl_xor(v, off, 64);
    if (o > v) v = o;
  }
  return v;
}

// ---------------------------------------------------------------------------
// k_decode v5: 2 threads per anchor (lane pair l, l+32), split by class
// groups: half A = groups 0..3 + head + fg + writes; half B = groups 4..9.
// Grid (66,32) -> 8448 waves = 33/CU (full occupancy slots; 2x the TLP of all
// prior rounds) with ~half the per-thread dependent chain. Exact sequential
// order of s / slogv preserved by passing B's per-group logs individually via
// shuffles; the only reassociation is sumCl = sclA + sclB (~1 ulp on bceS).
// ---------------------------------------------------------------------------
__global__ __launch_bounds__(256) void k_decode(
    const float* __restrict__ f8, const float* __restrict__ f16, const float* __restrict__ f32x,
    const float* __restrict__ gtb, const int* __restrict__ ngts,
    float* __restrict__ boxes, float* __restrict__ boxesZ,
    float* __restrict__ objl, float* __restrict__ b0s,
    float* __restrict__ bceS, float* __restrict__ obsA,
    int* __restrict__ fg, int* __restrict__ cnt, int* __restrict__ mtch){
  int b = blockIdx.y;
  int tid = threadIdx.x;
  int wid = tid >> 6, lane = tid & 63;
  int half = lane >> 5;              // 0 = A, 1 = B
  int l32 = lane & 31;
  int a = blockIdx.x*128 + wid*32 + l32;
  __shared__ float4 sg[kG];
  if (tid < kG) sg[tid] = ((const float4*)gtb)[b*kG + tid];
  __syncthreads();
  if (a >= kA) return;               // pair lanes (l, l+32) share a -> exit together
  int ng = ngts[b];
  const float* base; int hw, off; float st_; int gx, gy;
  if (a < 6400)      { base=f8;   hw=6400; off=a;        st_=8.0f;  gx=off%80; gy=off/80; }
  else if (a < 8000) { base=f16;  hw=1600; off=a-6400;   st_=16.0f; gx=off%40; gy=off/40; }
  else               { base=f32x; hw=400;  off=a-8000;   st_=32.0f; gx=off%20; gy=off/20; }
  const float* p0 = base + ((size_t)b*85)*hw + off;
  const float* pc = p0 + (size_t)5*hw;
  int idx = b*kA + a;

  float ob = p0[(size_t)4*hw];       // both halves load (identical value)
  float obs = sigm(ob);
  float so = fsqrt(obs);

  // ---- class half-loop: identical per-group arithmetic to prior rounds ----
  int gbase = half ? 4 : 0;
  int ngrp  = half ? 6 : 4;
  float lS[6], lV[6];
  float scl = 0.0f;
  #pragma unroll
  for (int gi = 0; gi < 6; ++gi){ lS[gi] = 0.0f; lV[gi] = 0.0f; }
  #pragma unroll
  for (int gi = 0; gi < 6; ++gi){
    if (gi < ngrp){
      int grp = gbase + gi;
      float prodS = 1.0f, prodV = 1.0f;
      #pragma unroll
      for (int j = 0; j < 8; ++j){
        float cv = pc[(size_t)(grp*8 + j)*hw];
        float u = fexp(-cv);
        float v = 1.0f + u;
        float pp = so * frsq(v);
        pp = fminf(fmaxf(pp, 1e-7f), 1.0f - 1e-7f);
        prodS *= (1.0f - pp);
        prodV *= v;
        scl += cv;
      }
      lS[gi] = flog(prodS);
      lV[gi] = flog(prodV);
    }
  }

  // ---- half A: head decode + fg + per-anchor writes ----
  if (half == 0){
    float t0 = p0[0];
    float t1 = p0[(size_t)hw];
    float t2 = p0[(size_t)2*hw];
    float t3 = p0[(size_t)3*hw];
    float4 bx;
    bx.x = (t0 + (float)gx) * st_;
    bx.y = (t1 + (float)gy) * st_;
    bx.z = fexp(t2) * st_;
    bx.w = fexp(t3) * st_;
    ((float4*)boxes)[idx] = bx;
    objl[idx] = ob;
    obsA[idx] = obs;
    cnt[idx] = 0;
    mtch[idx] = 0x7fffffff;
    float cx = ((float)gx + 0.5f)*st_;
    float cy = ((float)gy + 0.5f)*st_;
    int f = 0;
    for (int g = 0; g < ng; ++g){
      float4 gt = sg[g];
      bool in_box = (cx > gt.x - 0.5f*gt.z) && (cx < gt.x + 0.5f*gt.z)
                 && (cy > gt.y - 0.5f*gt.w) && (cy < gt.y + 0.5f*gt.w);
      bool in_ctr = (cx > gt.x - 2.5f*st_) && (cx < gt.x + 2.5f*st_)
                 && (cy > gt.y - 2.5f*st_) && (cy < gt.y + 2.5f*st_);
      if (in_box || in_ctr){ f = 1; break; }
    }
    fg[idx] = f;
    ((float4*)boxesZ)[idx] = f ? bx : make_float4(0.0f,0.0f,0.0f,0.0f);
  }

  // ---- assemble exact-order sums on half A ----
  float s = 0.0f, slogv = 0.0f;
  if (half == 0){
    #pragma unroll
    for (int gi = 0; gi < 4; ++gi){ s -= lS[gi]; slogv += lV[gi]; }
  }
  #pragma unroll
  for (int gi = 0; gi < 6; ++gi){
    float bs = __shfl(lS[gi], (lane + 32) & 63, 64);
    float bv = __shfl(lV[gi], (lane + 32) & 63, 64);
    if (half == 0){ s -= bs; slogv += bv; }
  }
  float sclB = __shfl(scl, (lane + 32) & 63, 64);
  if (half == 0){
    b0s[idx]  = s;
    bceS[idx] = (scl + sclB) + slogv;   // single reassociation vs sequential
  }
}

// ---------------------------------------------------------------------------
// k_assign: two-tier exact SimOTA assignment (unchanged from r3/r4).
// ---------------------------------------------------------------------------
__global__ __launch_bounds__(256) void k_assign(
    const float* __restrict__ f8, const float* __restrict__ f16, const float* __restrict__ f32x,
    const float* __restrict__ gtb, const int* __restrict__ gtc, const int* __restrict__ ngts,
    const float* __restrict__ boxes, const float* __restrict__ boxesZ,
    const float* __restrict__ obsA, const float* __restrict__ b0s,
    const int* __restrict__ fg,
    int* __restrict__ cnt, int* __restrict__ mtch){
  int b = blockIdx.x / kG;
  int g = blockIdx.x % kG;
  if (g >= ngts[b]) return;     // vmask (block-uniform)
  int tid = threadIdx.x;
  int lane = tid & 63, wid = tid >> 6;
  float4 gt = ((const float4*)gtb)[b*kG + g];
  int cls = gtc[b*kG + g];
  const float4* bx4 = (const float4*)boxes;
  const float4* bz4 = (const float4*)boxesZ;
  const float* c8  = f8   + ((size_t)b*85 + 5 + cls)*6400;
  const float* c16 = f16  + ((size_t)b*85 + 5 + cls)*1600;
  const float* c32 = f32x + ((size_t)b*85 + 5 + cls)*400;

  __shared__ unsigned long long lds_k[4*kK];
  __shared__ int lds_cnt[4];
  __shared__ int s_dynk;

  // ================= Tier A: iou top-10, fully coalesced =================
  unsigned long long k1[kK];
  #pragma unroll
  for (int i = 0; i < kK; ++i) k1[i] = 0ull;

  for (int i = tid; i < kA; i += 256){
    float4 bx = bz4[b*kA + i];
    float v = pair_iou(gt, bx);              // zero box -> inter=0 -> v=+0.0
    unsigned long long key1 = ((unsigned long long)ordbits(v) << 32) | (unsigned)(~i);
    if (key1 > k1[kK-1]){
      k1[kK-1] = key1;
      #pragma unroll
      for (int i2 = kK-1; i2 > 0; --i2)
        if (k1[i2] > k1[i2-1]){ unsigned long long t = k1[i2]; k1[i2] = k1[i2-1]; k1[i2-1] = t; }
    }
  }
  // wave-local extraction of wave top-10 (descending); lane r keeps r-th
  {
    unsigned long long wtop = 0ull;
    #pragma unroll
    for (int k = 0; k < kK; ++k){
      unsigned long long best = wave_max64(k1[0]);
      if (k1[0] == best){
        #pragma unroll
        for (int i2 = 0; i2 < kK-1; ++i2) k1[i2] = k1[i2+1];
        k1[kK-1] = 0ull;
      }
      if (lane == k) wtop = best;
    }
    if (lane < kK) lds_k[wid*kK + lane] = wtop;
  }
  __syncthreads();                                   // B1
  if (wid == 0){
    unsigned long long key = (lane < 4*kK) ? lds_k[lane] : 0ull;
    float ksum = 0.0f;
    #pragma unroll
    for (int k = 0; k < kK; ++k){
      unsigned long long best = wave_max64(key);
      if (key == best) key = 0ull;
      if (best) ksum += unpackf((unsigned)(best >> 32));  // global descending order, same as ref
    }
    if (lane == 0) s_dynk = max((int)ksum, 1);
  }
  __syncthreads();                                   // B2 (s_dynk ready, lds_k reusable)
  int dynk = s_dynk;

  // ================= Tier B: geometric in_both candidates =================
  int x00,y00,nx0,n0, x01,y01,nx1,n1, x02,y02,nx2,n2;
  {
    auto rect = [&](float st, int W, int& rx0, int& ry0, int& rnx, int& rn){
      float lox = fmaxf(gt.x - 0.5f*gt.z, gt.x - 2.5f*st);
      float hix = fminf(gt.x + 0.5f*gt.z, gt.x + 2.5f*st);
      float loy = fmaxf(gt.y - 0.5f*gt.w, gt.y - 2.5f*st);
      float hiy = fminf(gt.y + 0.5f*gt.w, gt.y + 2.5f*st);
      float rs = frcp(st);
      int ax0 = max(0,   (int)floorf(lox*rs - 0.5f) - 1);
      int ax1 = min(W-1, (int)ceilf (hix*rs - 0.5f) + 1);
      int ay0 = max(0,   (int)floorf(loy*rs - 0.5f) - 1);
      int ay1 = min(W-1, (int)ceilf (hiy*rs - 0.5f) + 1);
      rx0 = ax0; ry0 = ay0;
      rnx = max(0, ax1 - ax0 + 1);
      int rny = max(0, ay1 - ay0 + 1);
      rn = rnx * rny;
    };
    rect( 8.0f, 80, x00, y00, nx0, n0);
    rect(16.0f, 40, x01, y01, nx1, n1);
    rect(32.0f, 20, x02, y02, nx2, n2);
  }
  int total = n0 + n1 + n2;                // ≤ 3*81 = 243 < 256

  unsigned long long ck = 0ull;            // this thread's candidate cost key (0 = none)
  int nvalid = 0;
  if (tid < total){
    int i = tid, ix, iy, a; float st;
    if (i < n0)           { ix = x00 + i % nx0; iy = y00 + i / nx0; a = iy*80 + ix;          st = 8.0f;  }
    else if (i < n0 + n1) { int j = i - n0;      ix = x01 + j % nx1; iy = y01 + j / nx1; a = 6400 + iy*40 + ix; st = 16.0f; }
    else                  { int j = i - n0 - n1; ix = x02 + j % nx2; iy = y02 + j / nx2; a = 8000 + iy*20 + ix; st = 32.0f; }
    float cx = ((float)ix + 0.5f)*st;
    float cy = ((float)iy + 0.5f)*st;
    bool in_box = (cx > gt.x - 0.5f*gt.z) && (cx < gt.x + 0.5f*gt.z)
               && (cy > gt.y - 0.5f*gt.w) && (cy < gt.y + 0.5f*gt.w);
    bool in_ctr = (cx > gt.x - 2.5f*st) && (cx < gt.x + 2.5f*st)
               && (cy > gt.y - 2.5f*st) && (cy < gt.y + 2.5f*st);
    if (in_box && in_ctr){
      int idx = b*kA + a;
      float4 bx = bx4[idx];
      float iou = pair_iou(gt, bx);
      float cl = (a < 6400) ? c8[a] : (a < 8000) ? c16[a-6400] : c32[a-8000];
      float c = cost_core(iou, cl, obsA[idx], b0s[idx], a, gt, 1);  // in_both => fg=1
      ck = ~(((unsigned long long)ordbits(c) << 32) | (unsigned)a);
      nvalid = 1;
    }
  }
  {
    unsigned long long bal = __ballot(nvalid);
    if (lane == 0) lds_cnt[wid] = __popcll(bal);
    unsigned long long wtop = 0ull;
    #pragma unroll
    for (int k = 0; k < kK; ++k){
      unsigned long long best = wave_max64(ck);
      if (ck == best) ck = 0ull;
      if (lane == k) wtop = best;
    }
    if (lane < kK) lds_k[wid*kK + lane] = wtop;
  }
  __syncthreads();                                   // B3
  int cnt_total = lds_cnt[0] + lds_cnt[1] + lds_cnt[2] + lds_cnt[3];
  bool fb = (dynk > cnt_total);                      // block-uniform

  if (!fb){
    if (wid == 0){
      unsigned long long key = (lane < 4*kK) ? lds_k[lane] : 0ull;
      unsigned long long mine = 0ull;
      #pragma unroll
      for (int k = 0; k < kK; ++k){
        unsigned long long best = wave_max64(key);
        if (key == best) key = 0ull;
        if (lane == k) mine = best;
      }
      if (lane < dynk && mine){
        int a = (int)((unsigned)(~mine));
        atomicAdd(&cnt[b*kA + a], 1);    // scattered addresses: no same-line contention
        atomicMin(&mtch[b*kA + a], g);
      }
    }
    return;
  }

  // ================= Fallback: exact full cost scan (rare) =================
  __syncthreads();                                   // B4: lds_k reuse fence
  unsigned long long k2[kK];
  #pragma unroll
  for (int i = 0; i < kK; ++i) k2[i] = 0ull;
  for (int i = tid; i < kA; i += 256){
    int idx = b*kA + i;
    float4 bx = bx4[idx];
    float iou = pair_iou(gt, bx);
    int fga = fg[idx];
    float cl = (i < 6400) ? c8[i] : (i < 8000) ? c16[i-6400] : c32[i-8000];
    float c = cost_core(iou, cl, obsA[idx], b0s[idx], i, gt, fga);
    unsigned long long key2 = ~(((unsigned long long)ordbits(c) << 32) | (unsigned)i);
    if (key2 > k2[kK-1]){
      k2[kK-1] = key2;
      #pragma unroll
      for (int i2 = kK-1; i2 > 0; --i2)
        if (k2[i2] > k2[i2-1]){ unsigned long long t = k2[i2]; k2[i2] = k2[i2-1]; k2[i2-1] = t; }
    }
  }
  {
    unsigned long long wtop = 0ull;
    #pragma unroll
    for (int k = 0; k < kK; ++k){
      unsigned long long best = wave_max64(k2[0]);
      if (k2[0] == best){
        #pragma unroll
        for (int i2 = 0; i2 < kK-1; ++i2) k2[i2] = k2[i2+1];
        k2[kK-1] = 0ull;
      }
      if (lane == k) wtop = best;
    }
    if (lane < kK) lds_k[wid*kK + lane] = wtop;
  }
  __syncthreads();                                   // B5
  if (wid == 0){
    unsigned long long key = (lane < 4*kK) ? lds_k[lane] : 0ull;
    unsigned long long mine = 0ull;
    #pragma unroll
    for (int k = 0; k < kK; ++k){
      unsigned long long best = wave_max64(key);
      if (key == best) key = 0ull;
      if (lane == k) mine = best;
    }
    if (lane < dynk && mine){
      int a = (int)((unsigned)(~mine));
      atomicAdd(&cnt[b*kA + a], 1);
      atomicMin(&mtch[b*kA + a], g);
    }
  }
}

// ---------------------------------------------------------------------------
// k_loss with fused final reduction (last-block-done): removes the k_final
// launch. done zeroed via 4B hipMemsetAsync; device-scope atomics + fences
// order pacc writes across XCDs.
// ---------------------------------------------------------------------------
__global__ __launch_bounds__(256) void k_loss(
    const float* __restrict__ f8, const float* __restrict__ f16, const float* __restrict__ f32x,
    const float* __restrict__ gtb, const int* __restrict__ gtc, const int* __restrict__ ngts,
    const float* __restrict__ boxes, const float* __restrict__ objl, const float* __restrict__ b0s,
    const float* __restrict__ bceS, const float* __restrict__ obsA,
    const int* __restrict__ fg, const int* __restrict__ cnt, const int* __restrict__ mtch,
    float4* __restrict__ pacc, int* __restrict__ done, float* __restrict__ out){
  int b = blockIdx.y;
  int a = blockIdx.x*256 + threadIdx.x;
  int tid = threadIdx.x;
  __shared__ float4 sg[kG];
  __shared__ int scls[kG];
  __shared__ int slast;
  if (tid < kG){ sg[tid] = ((const float4*)gtb)[b*kG + tid]; scls[tid] = gtc[b*kG + tid]; }
  __syncthreads();
  float li = 0.0f, lo = 0.0f, lc = 0.0f, nf = 0.0f;
  bool valid = (a < kA);
  int idx = valid ? (b*kA + a) : (b*kA);
  int c = valid ? cnt[idx] : 0;
  float ob = valid ? objl[idx] : 0.0f;
  float4 bx = valid ? ((const float4*)boxes)[idx] : make_float4(0,0,1,1);

  float fgf = 0.0f; int mg = 0;
  if (valid && c == 1){ mg = mtch[idx]; fgf = 1.0f; }
  bool need = valid && (c > 1);
  if (__any(need)){
    if (need){
      int ng = ngts[b];
      float b0 = b0s[idx];
      float obs = obsA[idx];
      int fga = fg[idx];
      float bestc = 3.0e38f; int bg = 0;
      for (int g = 0; g < ng; ++g){
        float iou = pair_iou(sg[g], bx);
        float cl = featv(f8,f16,f32x,b,5+scls[g],a);
        float cst = cost_core(iou, cl, obs, b0, a, sg[g], fga);
        if (cst < bestc){ bestc = cst; bg = g; }   // strict <: first min = jnp.argmin
      }
      mg = bg; fgf = 1.0f;
    }
  }
  if (valid){
    lo = bce(ob, fgf*0.9f);
    if (fgf > 0.0f){
      nf = 1.0f;
      float4 r = sg[mg];
      float piou = pair_iou(r, bx);
      float tlx = fmaxf(bx.x - bx.z*0.5f, r.x - r.z*0.5f);
      float tly = fmaxf(bx.y - bx.w*0.5f, r.y - r.w*0.5f);
      float brx = fminf(bx.x + bx.z*0.5f, r.x + r.z*0.5f);
      float bry = fminf(bx.y + bx.w*0.5f, r.y + r.w*0.5f);
      float inter = (tlx < brx && tly < bry) ? (brx-tlx)*(bry-tly) : 0.0f;
      float un = bx.z*bx.w + r.z*r.w - inter;
      float iou = fdiv(inter, un + 1e-16f);
      li = 1.0f - iou*iou;
      int tc = scls[mg];
      float cl_tc = featv(f8,f16,f32x,b,5+tc,a);
      lc = bceS[idx] - piou * cl_tc;   // linearity of bce in target
    }
  }
  for (int off = 32; off > 0; off >>= 1){
    li += __shfl_down(li, off, 64);
    lo += __shfl_down(lo, off, 64);
    lc += __shfl_down(lc, off, 64);
    nf += __shfl_down(nf, off, 64);
  }
  __shared__ float4 wred[4];
  int wid = tid >> 6;
  if ((tid & 63) == 0) wred[wid] = make_float4(li, lo, lc, nf);
  __syncthreads();
  if (tid == 0){
    float4 t = wred[0];
    for (int w = 1; w < 4; ++w){
      float4 o = wred[w];
      t.x += o.x; t.y += o.y; t.z += o.z; t.w += o.w;
    }
    pacc[blockIdx.y * gridDim.x + blockIdx.x] = t;
    __threadfence();                          // release pacc write (device scope)
    int prev = atomicAdd(done, 1);            // device-scope by default
    slast = (prev == kNB - 1) ? 1 : 0;
  }
  __syncthreads();
  if (slast){
    __threadfence();                          // acquire side
    float fi = 0.0f, fo = 0.0f, fc = 0.0f, fn = 0.0f;
    const volatile float4* vp = (const volatile float4*)pacc;
    for (int i = tid; i < kNB; i += 256){
      float4 p; p.x = vp[i].x; p.y = vp[i].y; p.z = vp[i].z; p.w = vp[i].w;
      fi += p.x; fo += p.y; fc += p.z; fn += p.w;
    }
    for (int off = 32; off > 0; off >>= 1){
      fi += __shfl_down(fi, off, 64);
      fo += __shfl_down(fo, off, 64);
      fc += __shfl_down(fc, off, 64);
      fn += __shfl_down(fn, off, 64);
    }
    if ((tid & 63) == 0) wred[wid] = make_float4(fi, fo, fc, fn);
    __syncthreads();
    if (tid == 0){
      float4 t = wred[0];
      for (int w = 1; w < 4; ++w){
        float4 o = wred[w];
        t.x += o.x; t.y += o.y; t.z += o.z; t.w += o.w;
      }
      out[0] = (5.0f*t.x + t.y + t.z) * frcp(fmaxf(t.w, 1.0f));
    }
  }
}

extern "C" void kernel_launch(void* const* d_in, const int* in_sizes, int n_in,
                              void* d_out, int out_size, void* d_ws, size_t ws_size,
                              hipStream_t stream) {
  (void)in_sizes; (void)n_in; (void)out_size; (void)ws_size;
  const float* f8   = (const float*)d_in[0];
  const float* f16  = (const float*)d_in[1];
  const float* f32x = (const float*)d_in[2];
  const float* gtb  = (const float*)d_in[3];
  const int*   gtc  = (const int*)d_in[4];
  const int*   ngts = (const int*)d_in[5];
  float* out = (float*)d_out;

  const size_t BA = (size_t)kB*kA;
  float* ws     = (float*)d_ws;
  float* boxes  = ws;                              // 4*BA f32
  float* boxesZ = boxes  + BA*4;                   // 4*BA f32 (fg-masked boxes)
  float* objl   = boxesZ + BA*4;
  float* b0s    = objl   + BA;
  float* bceS   = b0s    + BA;
  float* obsA   = bceS   + BA;
  int*   fg     = (int*)(obsA + BA);
  int*   cnt    = fg  + BA;
  int*   mtch   = cnt + BA;
  float4* pacc  = (float4*)(mtch + BA);            // kNB float4 partials
  int*   done   = (int*)(pacc + kNB);              // 1 int

  hipMemsetAsync(done, 0, sizeof(int), stream);    // 4 B, graph-capture-safe
  dim3 gD(kNDx, kB);
  k_decode<<<gD, dim3(256), 0, stream>>>(f8,f16,f32x,gtb,ngts,boxes,boxesZ,objl,b0s,bceS,obsA,fg,cnt,mtch);
  k_assign<<<dim3(kB*kG), dim3(256), 0, stream>>>(f8,f16,f32x,gtb,gtc,ngts,boxes,boxesZ,obsA,b0s,fg,cnt,mtch);
  dim3 gBA(kNBx, kB);
  k_loss<<<gBA, dim3(256), 0, stream>>>(f8,f16,f32x,gtb,gtc,ngts,boxes,objl,b0s,bceS,obsA,fg,cnt,mtch,pacc,done,out);
}

// Round 6
// 198.663 us; speedup vs baseline: 1.1230x; 1.1230x over previous
//
#include <hip/hip_runtime.h>

constexpr int kB = 32;      // batch
constexpr int kA = 8400;    // anchors total (80*80 + 40*40 + 20*20)
constexpr int kG = 60;      // max GTs
constexpr int kC = 80;      // classes
constexpr int kK = 10;      // top-k
constexpr int kNBx = (kA + 255)/256;    // 33 blocks per batch
constexpr int kNB = kNBx * kB;          // 1056 loss blocks

// ---- HW-native fast math ----
__device__ __forceinline__ float fexp(float x){ return __expf(x); }
__device__ __forceinline__ float flog(float x){ return __logf(x); }
__device__ __forceinline__ float frcp(float x){ return __builtin_amdgcn_rcpf(x); }
__device__ __forceinline__ float frsq(float x){ return __builtin_amdgcn_rsqf(x); }
__device__ __forceinline__ float fsqrt(float x){ return __builtin_amdgcn_sqrtf(x); }
__device__ __forceinline__ float fdiv(float a, float b){ return a * __builtin_amdgcn_rcpf(b); }
__device__ __forceinline__ float sigm(float x){ return frcp(1.0f + fexp(-x)); }
__device__ __forceinline__ float bce(float x, float t){
  return fmaxf(x, 0.0f) - x*t + flog(1.0f + fexp(-fabsf(x)));
}

// monotone float -> u32 (total order)
__device__ __forceinline__ unsigned ordbits(float v){
  unsigned u = __float_as_uint(v);
  return (u & 0x80000000u) ? ~u : (u | 0x80000000u);
}
__device__ __forceinline__ float unpackf(unsigned k){
  return __uint_as_float((k & 0x80000000u) ? (k & 0x7fffffffu) : ~k);
}

struct AInfo { int x, y; float st; };
__device__ __forceinline__ AInfo ainfo(int a){
  AInfo r;
  if (a < 6400)      { r.x = a % 80;           r.y = a / 80;           r.st = 8.0f;  }
  else if (a < 8000) { int l = a-6400; r.x = l % 40; r.y = l / 40;     r.st = 16.0f; }
  else               { int l = a-8000; r.x = l % 20; r.y = l / 20;     r.st = 32.0f; }
  return r;
}

__device__ __forceinline__ float featv(const float* __restrict__ f8,
                                       const float* __restrict__ f16,
                                       const float* __restrict__ f32x,
                                       int b, int ch, int a){
  if (a < 6400) return f8 [(b*85 + ch)*6400 + a];
  if (a < 8000) return f16[(b*85 + ch)*1600 + (a - 6400)];
  return             f32x[(b*85 + ch)*400  + (a - 8000)];
}

__device__ __forceinline__ float pair_iou(float4 g, float4 p){
  float tlx = fmaxf(g.x - g.z*0.5f, p.x - p.z*0.5f);
  float tly = fmaxf(g.y - g.w*0.5f, p.y - p.w*0.5f);
  float brx = fminf(g.x + g.z*0.5f, p.x + p.z*0.5f);
  float bry = fminf(g.y + g.w*0.5f, p.y + p.w*0.5f);
  float inter = (tlx < brx && tly < bry) ? (brx-tlx)*(bry-tly) : 0.0f;
  return fdiv(inter, g.z*g.w + p.z*p.w - inter + 1e-16f);
}

// cost given precomputed iou and obj sigmoid — shared by k_assign / k_loss
__device__ __forceinline__ float cost_core(float iou, float cl, float obs, float b0sum,
                                           int a, float4 gt, int fg_a){
  AInfo ai = ainfo(a);
  float cx = ((float)ai.x + 0.5f)*ai.st;
  float cy = ((float)ai.y + 0.5f)*ai.st;
  bool in_box = (cx > gt.x - 0.5f*gt.z) && (cx < gt.x + 0.5f*gt.z)
             && (cy > gt.y - 0.5f*gt.w) && (cy < gt.y + 0.5f*gt.w);
  bool in_ctr = (cx > gt.x - 2.5f*ai.st) && (cx < gt.x + 2.5f*ai.st)
             && (cy > gt.y - 2.5f*ai.st) && (cy < gt.y + 2.5f*ai.st);
  float p = fsqrt(sigm(cl) * obs);
  p = fminf(fmaxf(p, 1e-7f), 1.0f - 1e-7f);
  float diff = -flog(p) + flog(1.0f - p);      // bce1 - bce0 at class cls
  float c = b0sum + diff;
  c += 3.0f * (-flog(iou + 1e-8f));
  c += (in_box && in_ctr) ? 0.0f : 100000.0f;
  c += fg_a ? 0.0f : 1000000000.0f;
  return c;
}

__device__ __forceinline__ unsigned long long wave_max64(unsigned long long v){
  #pragma unroll
  for (int off = 32; off; off >>= 1){
    unsigned long long o = __shfl_xor(v, off, 64);
    if (o > v) v = o;
  }
  return v;
}

// async global->LDS staging of one float per lane (no VGPR round-trip)
__device__ __forceinline__ void stage1(const float* g, float* l){
  __builtin_amdgcn_global_load_lds(
      (const __attribute__((address_space(1))) void*)g,
      (__attribute__((address_space(3))) void*)l, 4, 0, 0);
}
// compile-time vmcnt wait (N = allowed outstanding vmem ops) + scheduler fence
__device__ __forceinline__ void wait_vm(int n){
  if      (n >= 24) asm volatile("s_waitcnt vmcnt(24)" ::: "memory");
  else if (n >= 16) asm volatile("s_waitcnt vmcnt(16)" ::: "memory");
  else if (n >= 8)  asm volatile("s_waitcnt vmcnt(8)"  ::: "memory");
  else              asm volatile("s_waitcnt vmcnt(0)"  ::: "memory");
  __builtin_amdgcn_sched_barrier(0);
}

// ---------------------------------------------------------------------------
// k_decode v6: async global_load_lds pipeline, depth 4. Each wave owns a
// private 64-anchor column slice of buf (no cross-wave sharing -> no barriers
// in the pipeline). Per group g: counted vmcnt wait, LDS->reg, lgkm drain,
// restage group g+4 into the freed slot, compute. Loads are fire-and-forget
// (no VGPR cost, compiler cannot sink them) -> ~24 loads (6 KB) in flight per
// wave through the whole class loop. Stores all moved after the loop so vmcnt
// counts only our loads. Arithmetic sequence identical to r1/r3/r4.
// ---------------------------------------------------------------------------
__global__ __launch_bounds__(256) void k_decode(
    const float* __restrict__ f8, const float* __restrict__ f16, const float* __restrict__ f32x,
    const float* __restrict__ gtb, const int* __restrict__ ngts,
    float* __restrict__ boxes, float* __restrict__ boxesZ,
    float* __restrict__ objl, float* __restrict__ b0s,
    float* __restrict__ bceS, float* __restrict__ obsA,
    int* __restrict__ fg, int* __restrict__ cnt, int* __restrict__ mtch){
  int b = blockIdx.y;
  int tid = threadIdx.x;
  int a0 = blockIdx.x*256 + tid;
  bool alive = (a0 < kA);
  int a = alive ? a0 : (kA - 1);     // clamp OOB lanes to a valid address (stores guarded)
  __shared__ float4 sg[kG];
  __shared__ float buf[4][8][256];   // 32 KB staging, 4-deep
  if (tid < kG) sg[tid] = ((const float4*)gtb)[b*kG + tid];
  int ng = ngts[b];
  __syncthreads();                   // drains the sg loads (vmcnt->0) before pipeline starts

  const float* base; int hw, off; float st_; int gx, gy;
  if (a < 6400)      { base=f8;   hw=6400; off=a;        st_=8.0f;  gx=off%80; gy=off/80; }
  else if (a < 8000) { base=f16;  hw=1600; off=a-6400;   st_=16.0f; gx=off%40; gy=off/40; }
  else               { base=f32x; hw=400;  off=a-8000;   st_=32.0f; gx=off%20; gy=off/20; }
  const float* p0 = base + ((size_t)b*85)*hw + off;
  const float* pc = p0 + (size_t)5*hw;
  int wbase = (tid >> 6) * 64;       // this wave's private LDS column base

  // ---- head loads first (oldest in the vmem queue) ----
  float t0 = p0[0];
  float t1 = p0[(size_t)hw];
  float t2 = p0[(size_t)2*hw];
  float t3 = p0[(size_t)3*hw];
  float ob = p0[(size_t)4*hw];
  __builtin_amdgcn_sched_barrier(0);
  // ---- prologue: stage groups 0..3 (8 async loads each) ----
  #pragma unroll
  for (int g = 0; g < 4; ++g)
    #pragma unroll
    for (int j = 0; j < 8; ++j)
      stage1(pc + (size_t)(g*8 + j)*hw, &buf[g][j][wbase]);
  __builtin_amdgcn_sched_barrier(0);

  // ---- head compute (compiler auto-waits only the 5 head loads) ----
  float4 bx;
  bx.x = (t0 + (float)gx) * st_;
  bx.y = (t1 + (float)gy) * st_;
  bx.z = fexp(t2) * st_;
  bx.w = fexp(t3) * st_;
  float obs = sigm(ob);
  float so = fsqrt(obs);
  // ---- fg test (VALU + LDS-sg only; overlaps staging latency) ----
  float cx = ((float)gx + 0.5f)*st_;
  float cy = ((float)gy + 0.5f)*st_;
  int f = 0;
  for (int g = 0; g < ng; ++g){
    float4 gt = sg[g];
    bool in_box = (cx > gt.x - 0.5f*gt.z) && (cx < gt.x + 0.5f*gt.z)
               && (cy > gt.y - 0.5f*gt.w) && (cy < gt.y + 0.5f*gt.w);
    bool in_ctr = (cx > gt.x - 2.5f*st_) && (cx < gt.x + 2.5f*st_)
               && (cy > gt.y - 2.5f*st_) && (cy < gt.y + 2.5f*st_);
    if (in_box || in_ctr){ f = 1; break; }
  }

  // ---- class pipeline ----
  float s = 0.0f, sumCl = 0.0f, slogv = 0.0f;
  #pragma unroll
  for (int g = 0; g < 10; ++g){
    int rem = (9 - g < 3) ? (9 - g) : 3;      // groups still in flight after g
    wait_vm(8 * rem);                          // group g's 8 loads landed in LDS
    float cv[8];
    #pragma unroll
    for (int j = 0; j < 8; ++j) cv[j] = buf[g & 3][j][tid];
    asm volatile("s_waitcnt lgkmcnt(0)" ::: "memory");  // reads retired before overwrite
    __builtin_amdgcn_sched_barrier(0);
    if (g + 4 < 10){
      #pragma unroll
      for (int j = 0; j < 8; ++j)
        stage1(pc + (size_t)((g+4)*8 + j)*hw, &buf[g & 3][j][wbase]);
    }
    __builtin_amdgcn_sched_barrier(0);
    float prodS = 1.0f, prodV = 1.0f;
    #pragma unroll
    for (int j = 0; j < 8; ++j){
      float c = cv[j];
      float u = fexp(-c);
      float v = 1.0f + u;
      float p = so * frsq(v);
      p = fminf(fmaxf(p, 1e-7f), 1.0f - 1e-7f);
      prodS *= (1.0f - p);
      prodV *= v;
      sumCl += c;
    }
    s -= flog(prodS);
    slogv += flog(prodV);
  }
  __builtin_amdgcn_sched_barrier(0);
  // ---- all stores at the end (outside the counted-vmcnt window) ----
  if (alive){
    int idx = b*kA + a;
    ((float4*)boxes)[idx] = bx;
    objl[idx] = ob;
    obsA[idx] = obs;
    cnt[idx] = 0;
    mtch[idx] = 0x7fffffff;
    fg[idx] = f;
    ((float4*)boxesZ)[idx] = f ? bx : make_float4(0.0f,0.0f,0.0f,0.0f);
    b0s[idx]  = s;
    bceS[idx] = sumCl + slogv;
  }
}

// ---------------------------------------------------------------------------
// k_assign: two-tier exact SimOTA assignment (unchanged from r3/r4).
// ---------------------------------------------------------------------------
__global__ __launch_bounds__(256) void k_assign(
    const float* __restrict__ f8, const float* __restrict__ f16, const float* __restrict__ f32x,
    const float* __restrict__ gtb, const int* __restrict__ gtc, const int* __restrict__ ngts,
    const float* __restrict__ boxes, const float* __restrict__ boxesZ,
    const float* __restrict__ obsA, const float* __restrict__ b0s,
    const int* __restrict__ fg,
    int* __restrict__ cnt, int* __restrict__ mtch){
  int b = blockIdx.x / kG;
  int g = blockIdx.x % kG;
  if (g >= ngts[b]) return;     // vmask (block-uniform)
  int tid = threadIdx.x;
  int lane = tid & 63, wid = tid >> 6;
  float4 gt = ((const float4*)gtb)[b*kG + g];
  int cls = gtc[b*kG + g];
  const float4* bx4 = (const float4*)boxes;
  const float4* bz4 = (const float4*)boxesZ;
  const float* c8  = f8   + ((size_t)b*85 + 5 + cls)*6400;
  const float* c16 = f16  + ((size_t)b*85 + 5 + cls)*1600;
  const float* c32 = f32x + ((size_t)b*85 + 5 + cls)*400;

  __shared__ unsigned long long lds_k[4*kK];
  __shared__ int lds_cnt[4];
  __shared__ int s_dynk;

  // ================= Tier A: iou top-10, fully coalesced =================
  unsigned long long k1[kK];
  #pragma unroll
  for (int i = 0; i < kK; ++i) k1[i] = 0ull;

  for (int i = tid; i < kA; i += 256){
    float4 bx = bz4[b*kA + i];
    float v = pair_iou(gt, bx);              // zero box -> inter=0 -> v=+0.0
    unsigned long long key1 = ((unsigned long long)ordbits(v) << 32) | (unsigned)(~i);
    if (key1 > k1[kK-1]){
      k1[kK-1] = key1;
      #pragma unroll
      for (int i2 = kK-1; i2 > 0; --i2)
        if (k1[i2] > k1[i2-1]){ unsigned long long t = k1[i2]; k1[i2] = k1[i2-1]; k1[i2-1] = t; }
    }
  }
  // wave-local extraction of wave top-10 (descending); lane r keeps r-th
  {
    unsigned long long wtop = 0ull;
    #pragma unroll
    for (int k = 0; k < kK; ++k){
      unsigned long long best = wave_max64(k1[0]);
      if (k1[0] == best){
        #pragma unroll
        for (int i2 = 0; i2 < kK-1; ++i2) k1[i2] = k1[i2+1];
        k1[kK-1] = 0ull;
      }
      if (lane == k) wtop = best;
    }
    if (lane < kK) lds_k[wid*kK + lane] = wtop;
  }
  __syncthreads();                                   // B1
  if (wid == 0){
    unsigned long long key = (lane < 4*kK) ? lds_k[lane] : 0ull;
    float ksum = 0.0f;
    #pragma unroll
    for (int k = 0; k < kK; ++k){
      unsigned long long best = wave_max64(key);
      if (key == best) key = 0ull;
      if (best) ksum += unpackf((unsigned)(best >> 32));  // global descending order, same as ref
    }
    if (lane == 0) s_dynk = max((int)ksum, 1);
  }
  __syncthreads();                                   // B2 (s_dynk ready, lds_k reusable)
  int dynk = s_dynk;

  // ================= Tier B: geometric in_both candidates =================
  int x00,y00,nx0,n0, x01,y01,nx1,n1, x02,y02,nx2,n2;
  {
    auto rect = [&](float st, int W, int& rx0, int& ry0, int& rnx, int& rn){
      float lox = fmaxf(gt.x - 0.5f*gt.z, gt.x - 2.5f*st);
      float hix = fminf(gt.x + 0.5f*gt.z, gt.x + 2.5f*st);
      float loy = fmaxf(gt.y - 0.5f*gt.w, gt.y - 2.5f*st);
      float hiy = fminf(gt.y + 0.5f*gt.w, gt.y + 2.5f*st);
      float rs = frcp(st);
      int ax0 = max(0,   (int)floorf(lox*rs - 0.5f) - 1);
      int ax1 = min(W-1, (int)ceilf (hix*rs - 0.5f) + 1);
      int ay0 = max(0,   (int)floorf(loy*rs - 0.5f) - 1);
      int ay1 = min(W-1, (int)ceilf (hiy*rs - 0.5f) + 1);
      rx0 = ax0; ry0 = ay0;
      rnx = max(0, ax1 - ax0 + 1);
      int rny = max(0, ay1 - ay0 + 1);
      rn = rnx * rny;
    };
    rect( 8.0f, 80, x00, y00, nx0, n0);
    rect(16.0f, 40, x01, y01, nx1, n1);
    rect(32.0f, 20, x02, y02, nx2, n2);
  }
  int total = n0 + n1 + n2;                // ≤ 3*81 = 243 < 256

  unsigned long long ck = 0ull;            // this thread's candidate cost key (0 = none)
  int nvalid = 0;
  if (tid < total){
    int i = tid, ix, iy, a; float st;
    if (i < n0)           { ix = x00 + i % nx0; iy = y00 + i / nx0; a = iy*80 + ix;          st = 8.0f;  }
    else if (i < n0 + n1) { int j = i - n0;      ix = x01 + j % nx1; iy = y01 + j / nx1; a = 6400 + iy*40 + ix; st = 16.0f; }
    else                  { int j = i - n0 - n1; ix = x02 + j % nx2; iy = y02 + j / nx2; a = 8000 + iy*20 + ix; st = 32.0f; }
    float cx = ((float)ix + 0.5f)*st;
    float cy = ((float)iy + 0.5f)*st;
    bool in_box = (cx > gt.x - 0.5f*gt.z) && (cx < gt.x + 0.5f*gt.z)
               && (cy > gt.y - 0.5f*gt.w) && (cy < gt.y + 0.5f*gt.w);
    bool in_ctr = (cx > gt.x - 2.5f*st) && (cx < gt.x + 2.5f*st)
               && (cy > gt.y - 2.5f*st) && (cy < gt.y + 2.5f*st);
    if (in_box && in_ctr){
      int idx = b*kA + a;
      float4 bx = bx4[idx];
      float iou = pair_iou(gt, bx);
      float cl = (a < 6400) ? c8[a] : (a < 8000) ? c16[a-6400] : c32[a-8000];
      float c = cost_core(iou, cl, obsA[idx], b0s[idx], a, gt, 1);  // in_both => fg=1
      ck = ~(((unsigned long long)ordbits(c) << 32) | (unsigned)a);
      nvalid = 1;
    }
  }
  {
    unsigned long long bal = __ballot(nvalid);
    if (lane == 0) lds_cnt[wid] = __popcll(bal);
    unsigned long long wtop = 0ull;
    #pragma unroll
    for (int k = 0; k < kK; ++k){
      unsigned long long best = wave_max64(ck);
      if (ck == best) ck = 0ull;
      if (lane == k) wtop = best;
    }
    if (lane < kK) lds_k[wid*kK + lane] = wtop;
  }
  __syncthreads();                                   // B3
  int cnt_total = lds_cnt[0] + lds_cnt[1] + lds_cnt[2] + lds_cnt[3];
  bool fb = (dynk > cnt_total);                      // block-uniform

  if (!fb){
    if (wid == 0){
      unsigned long long key = (lane < 4*kK) ? lds_k[lane] : 0ull;
      unsigned long long mine = 0ull;
      #pragma unroll
      for (int k = 0; k < kK; ++k){
        unsigned long long best = wave_max64(key);
        if (key == best) key = 0ull;
        if (lane == k) mine = best;
      }
      if (lane < dynk && mine){
        int a = (int)((unsigned)(~mine));
        atomicAdd(&cnt[b*kA + a], 1);    // scattered addresses: no same-line contention
        atomicMin(&mtch[b*kA + a], g);
      }
    }
    return;
  }

  // ================= Fallback: exact full cost scan (rare) =================
  __syncthreads();                                   // B4: lds_k reuse fence
  unsigned long long k2[kK];
  #pragma unroll
  for (int i = 0; i < kK; ++i) k2[i] = 0ull;
  for (int i = tid; i < kA; i += 256){
    int idx = b*kA + i;
    float4 bx = bx4[idx];
    float iou = pair_iou(gt, bx);
    int fga = fg[idx];
    float cl = (i < 6400) ? c8[i] : (i < 8000) ? c16[i-6400] : c32[i-8000];
    float c = cost_core(iou, cl, obsA[idx], b0s[idx], i, gt, fga);
    unsigned long long key2 = ~(((unsigned long long)ordbits(c) << 32) | (unsigned)i);
    if (key2 > k2[kK-1]){
      k2[kK-1] = key2;
      #pragma unroll
      for (int i2 = kK-1; i2 > 0; --i2)
        if (k2[i2] > k2[i2-1]){ unsigned long long t = k2[i2]; k2[i2] = k2[i2-1]; k2[i2-1] = t; }
    }
  }
  {
    unsigned long long wtop = 0ull;
    #pragma unroll
    for (int k = 0; k < kK; ++k){
      unsigned long long best = wave_max64(k2[0]);
      if (k2[0] == best){
        #pragma unroll
        for (int i2 = 0; i2 < kK-1; ++i2) k2[i2] = k2[i2+1];
        k2[kK-1] = 0ull;
      }
      if (lane == k) wtop = best;
    }
    if (lane < kK) lds_k[wid*kK + lane] = wtop;
  }
  __syncthreads();                                   // B5
  if (wid == 0){
    unsigned long long key = (lane < 4*kK) ? lds_k[lane] : 0ull;
    unsigned long long mine = 0ull;
    #pragma unroll
    for (int k = 0; k < kK; ++k){
      unsigned long long best = wave_max64(key);
      if (key == best) key = 0ull;
      if (lane == k) mine = best;
    }
    if (lane < dynk && mine){
      int a = (int)((unsigned)(~mine));
      atomicAdd(&cnt[b*kA + a], 1);
      atomicMin(&mtch[b*kA + a], g);
    }
  }
}

__global__ __launch_bounds__(256) void k_loss(
    const float* __restrict__ f8, const float* __restrict__ f16, const float* __restrict__ f32x,
    const float* __restrict__ gtb, const int* __restrict__ gtc, const int* __restrict__ ngts,
    const float* __restrict__ boxes, const float* __restrict__ objl, const float* __restrict__ b0s,
    const float* __restrict__ bceS, const float* __restrict__ obsA,
    const int* __restrict__ fg, const int* __restrict__ cnt, const int* __restrict__ mtch,
    float4* __restrict__ pacc){
  int b = blockIdx.y;
  int a = blockIdx.x*256 + threadIdx.x;
  int tid = threadIdx.x;
  __shared__ float4 sg[kG];
  __shared__ int scls[kG];
  if (tid < kG){ sg[tid] = ((const float4*)gtb)[b*kG + tid]; scls[tid] = gtc[b*kG + tid]; }
  __syncthreads();
  float li = 0.0f, lo = 0.0f, lc = 0.0f, nf = 0.0f;
  bool valid = (a < kA);
  int idx = valid ? (b*kA + a) : (b*kA);
  int c = valid ? cnt[idx] : 0;
  float ob = valid ? objl[idx] : 0.0f;
  float4 bx = valid ? ((const float4*)boxes)[idx] : make_float4(0,0,1,1);

  float fgf = 0.0f; int mg = 0;
  if (valid && c == 1){ mg = mtch[idx]; fgf = 1.0f; }
  bool need = valid && (c > 1);
  if (__any(need)){
    if (need){
      int ng = ngts[b];
      float b0 = b0s[idx];
      float obs = obsA[idx];
      int fga = fg[idx];
      float bestc = 3.0e38f; int bg = 0;
      for (int g = 0; g < ng; ++g){
        float iou = pair_iou(sg[g], bx);
        float cl = featv(f8,f16,f32x,b,5+scls[g],a);
        float cst = cost_core(iou, cl, obs, b0, a, sg[g], fga);
        if (cst < bestc){ bestc = cst; bg = g; }   // strict <: first min = jnp.argmin
      }
      mg = bg; fgf = 1.0f;
    }
  }
  if (valid){
    lo = bce(ob, fgf*0.9f);
    if (fgf > 0.0f){
      nf = 1.0f;
      float4 r = sg[mg];
      float piou = pair_iou(r, bx);
      float tlx = fmaxf(bx.x - bx.z*0.5f, r.x - r.z*0.5f);
      float tly = fmaxf(bx.y - bx.w*0.5f, r.y - r.w*0.5f);
      float brx = fminf(bx.x + bx.z*0.5f, r.x + r.z*0.5f);
      float bry = fminf(bx.y + bx.w*0.5f, r.y + r.w*0.5f);
      float inter = (tlx < brx && tly < bry) ? (brx-tlx)*(bry-tly) : 0.0f;
      float un = bx.z*bx.w + r.z*r.w - inter;
      float iou = fdiv(inter, un + 1e-16f);
      li = 1.0f - iou*iou;
      int tc = scls[mg];
      float cl_tc = featv(f8,f16,f32x,b,5+tc,a);
      lc = bceS[idx] - piou * cl_tc;   // linearity of bce in target
    }
  }
  for (int off = 32; off > 0; off >>= 1){
    li += __shfl_down(li, off, 64);
    lo += __shfl_down(lo, off, 64);
    lc += __shfl_down(lc, off, 64);
    nf += __shfl_down(nf, off, 64);
  }
  __shared__ float4 wred[4];
  int wid = tid >> 6;
  if ((tid & 63) == 0) wred[wid] = make_float4(li, lo, lc, nf);
  __syncthreads();
  if (tid == 0){
    float4 t = wred[0];
    for (int w = 1; w < 4; ++w){
      float4 o = wred[w];
      t.x += o.x; t.y += o.y; t.z += o.z; t.w += o.w;
    }
    pacc[blockIdx.y * gridDim.x + blockIdx.x] = t;
  }
}

__global__ __launch_bounds__(256) void k_final(
    const float4* __restrict__ pacc, float* __restrict__ out){
  int tid = threadIdx.x;
  float li = 0.0f, lo = 0.0f, lc = 0.0f, nf = 0.0f;
  for (int i = tid; i < kNB; i += 256){
    float4 p = pacc[i];
    li += p.x; lo += p.y; lc += p.z; nf += p.w;
  }
  for (int off = 32; off > 0; off >>= 1){
    li += __shfl_down(li, off, 64);
    lo += __shfl_down(lo, off, 64);
    lc += __shfl_down(lc, off, 64);
    nf += __shfl_down(nf, off, 64);
  }
  __shared__ float4 wred[4];
  int wid = tid >> 6;
  if ((tid & 63) == 0) wred[wid] = make_float4(li, lo, lc, nf);
  __syncthreads();
  if (tid == 0){
    float4 t = wred[0];
    for (int w = 1; w < 4; ++w){
      float4 o = wred[w];
      t.x += o.x; t.y += o.y; t.z += o.z; t.w += o.w;
    }
    out[0] = (5.0f*t.x + t.y + t.z) * frcp(fmaxf(t.w, 1.0f));
  }
}

extern "C" void kernel_launch(void* const* d_in, const int* in_sizes, int n_in,
                              void* d_out, int out_size, void* d_ws, size_t ws_size,
                              hipStream_t stream) {
  (void)in_sizes; (void)n_in; (void)out_size; (void)ws_size;
  const float* f8   = (const float*)d_in[0];
  const float* f16  = (const float*)d_in[1];
  const float* f32x = (const float*)d_in[2];
  const float* gtb  = (const float*)d_in[3];
  const int*   gtc  = (const int*)d_in[4];
  const int*   ngts = (const int*)d_in[5];
  float* out = (float*)d_out;

  const size_t BA = (size_t)kB*kA;
  float* ws     = (float*)d_ws;
  float* boxes  = ws;                              // 4*BA f32
  float* boxesZ = boxes  + BA*4;                   // 4*BA f32 (fg-masked boxes)
  float* objl   = boxesZ + BA*4;
  float* b0s    = objl   + BA;
  float* bceS   = b0s    + BA;
  float* obsA   = bceS   + BA;
  int*   fg     = (int*)(obsA + BA);
  int*   cnt    = fg  + BA;
  int*   mtch   = cnt + BA;
  float4* pacc  = (float4*)(mtch + BA);            // kNB float4 partials

  dim3 gBA(kNBx, kB);
  k_decode<<<gBA, dim3(256), 0, stream>>>(f8,f16,f32x,gtb,ngts,boxes,boxesZ,objl,b0s,bceS,obsA,fg,cnt,mtch);
  k_assign<<<dim3(kB*kG), dim3(256), 0, stream>>>(f8,f16,f32x,gtb,gtc,ngts,boxes,boxesZ,obsA,b0s,fg,cnt,mtch);
  k_loss<<<gBA, dim3(256), 0, stream>>>(f8,f16,f32x,gtb,gtc,ngts,boxes,objl,b0s,bceS,obsA,fg,cnt,mtch,pacc);
  k_final<<<dim3(1), dim3(256), 0, stream>>>(pacc, out);
}